// Round 3
// baseline (274.376 us; speedup 1.0000x reference)
//
#include <hip/hip_runtime.h>
#include <math.h>

// SoftPeakAwareLoss on MI355X — R1 (resubmit; R1 bench hit GPU-acquisition
// timeout, never measured): LDS-transpose staging.
// Each 256-thread block stages 256 days (24 h) of yp/yt via perfectly
// coalesced float4 loads into transposed LDS [hour][day] (+1 pad column,
// bank-conflict-free), packs is_daytime into per-day bitmasks via LDS
// atomicOr. Compute reads conflict-free columns; the +-2 window gather is
// 10 LDS reads (no cndmask chains). Block reduce -> float4 partial -> 1-block
// finalize in double.

#define HOURS_ 24
#define WIN_ 2
#define NEGV (-1e9f)
#define DPB 256        // days per block
#define LDP (DPB + 1)  // padded day stride (257 -> bank-free)

__global__ __launch_bounds__(256) void splloss_days(
    const float* __restrict__ ypred,
    const float* __restrict__ ytrue,
    const float* __restrict__ isday,
    float4* __restrict__ partials,
    int n_days)
{
    __shared__ float apT[HOURS_][LDP];      // pred, transposed [h][day]
    __shared__ float atT[HOURS_][LDP];      // true, transposed [h][day]
    __shared__ unsigned maskLds[DPB];       // per-day daytime bitmask

    const int tid  = threadIdx.x;
    const int day0 = blockIdx.x * DPB;
    const int vdays = min(DPB, n_days - day0);   // valid days this block
    const int vchunks = vdays * 6;               // valid float4 chunks

    // ---- issue all 18 coalesced global loads up front
    const float4* p4 = reinterpret_cast<const float4*>(ypred) + (size_t)day0 * 6;
    const float4* t4 = reinterpret_cast<const float4*>(ytrue) + (size_t)day0 * 6;
    const float4* d4 = reinterpret_cast<const float4*>(isday) + (size_t)day0 * 6;
    float4 vp[6], vt[6], vd[6];
    #pragma unroll
    for (int j = 0; j < 6; ++j) {
        int c = tid + j * 256;
        if (c < vchunks) { vp[j] = p4[c]; vt[j] = t4[c]; vd[j] = d4[c]; }
    }

    maskLds[tid] = 0u;
    __syncthreads();

    // ---- transpose into LDS (scalar writes, ~2 lanes/bank) + mask pack
    #pragma unroll
    for (int j = 0; j < 6; ++j) {
        int c = tid + j * 256;
        if (c < vchunks) {
            int day = c / 6;
            int h0  = (c - day * 6) * 4;
            apT[h0 + 0][day] = vp[j].x; apT[h0 + 1][day] = vp[j].y;
            apT[h0 + 2][day] = vp[j].z; apT[h0 + 3][day] = vp[j].w;
            atT[h0 + 0][day] = vt[j].x; atT[h0 + 1][day] = vt[j].y;
            atT[h0 + 2][day] = vt[j].z; atT[h0 + 3][day] = vt[j].w;
            unsigned bits = (vd[j].x > 0.5f ? 1u : 0u)
                          | (vd[j].y > 0.5f ? 2u : 0u)
                          | (vd[j].z > 0.5f ? 4u : 0u)
                          | (vd[j].w > 0.5f ? 8u : 0u);
            atomicOr(&maskLds[day], bits << h0);
        }
    }
    __syncthreads();

    // ---- per-day compute (thread tid owns day column tid)
    float o = 0.f, mg = 0.f, tl = 0.f, sh = 0.f;
    if (tid < vdays) {
        unsigned dmask = maskLds[tid];
        float a[HOURS_], b[HOURS_];
        #pragma unroll
        for (int h = 0; h < HOURS_; ++h) { a[h] = apT[h][tid]; b[h] = atT[h][tid]; }

        // L_overall partial + masked maxima + first-occurrence argmax on true
        float mt = -INFINITY, mp = -INFINITY;
        int peak = 0;
        #pragma unroll
        for (int h = 0; h < HOURS_; ++h) {
            float d = a[h] - b[h];
            o += d * d;
            bool day = (dmask >> h) & 1u;
            float bm = day ? b[h] : NEGV;
            float am = day ? a[h] : NEGV;
            if (bm > mt) { mt = bm; peak = h; }  // strict > = first occurrence
            mp = fmaxf(mp, am);
        }

        // soft peaks (softmax, TEMP=0.1 -> scale 10)
        float set = 0.f, syt = 0.f, sht = 0.f;
        float sep = 0.f, syp = 0.f, shp = 0.f;
        #pragma unroll
        for (int h = 0; h < HOURS_; ++h) {
            bool day = (dmask >> h) & 1u;
            float bm = day ? b[h] : NEGV;
            float am = day ? a[h] : NEGV;
            float et = __expf((bm - mt) * 10.f);  // night -> exp(-1e10) = 0
            float ep = __expf((am - mp) * 10.f);
            set += et; syt += et * b[h]; sht += et * (float)h;
            sep += ep; syp += ep * a[h]; shp += ep * (float)h;
        }
        float tv = syt / set, tt = sht / set;
        float pv = syp / sep, pt = shp / sep;
        mg = (pv - tv) * (pv - tv);
        tl = (pt - tt) * (pt - tt);

        // shape loss: gather +-2 window straight from LDS columns
        float tw[5], pw[5];
        float tmax = -INFINITY, pmax = -INFINITY, cnt = 0.f;
        bool val[5];
        #pragma unroll
        for (int j = 0; j < 5; ++j) {
            int idx = peak + j - WIN_;
            bool v = (idx >= 0) && (idx < HOURS_);
            int ic = idx < 0 ? 0 : (idx > HOURS_ - 1 ? HOURS_ - 1 : idx);
            float tg = atT[ic][tid];
            float pg = apT[ic][tid];
            tw[j] = tg; pw[j] = pg; val[j] = v;
            if (v) { tmax = fmaxf(tmax, tg); pmax = fmaxf(pmax, pg); cnt += 1.f; }
        }
        float rt = 1.f / (tmax + 1e-6f);
        float rp = 1.f / (pmax + 1e-6f);
        float ss = 0.f;
        #pragma unroll
        for (int j = 0; j < 5; ++j) {
            float tn = tw[j] * rt, pn = pw[j] * rp;
            float d = pn - tn;
            ss += val[j] ? d * d : 0.f;
        }
        sh = ss / cnt;
    }

    // ---- block reduction: wave shuffle then LDS across the 4 waves
    #pragma unroll
    for (int off = 32; off > 0; off >>= 1) {
        o  += __shfl_down(o,  off);
        mg += __shfl_down(mg, off);
        tl += __shfl_down(tl, off);
        sh += __shfl_down(sh, off);
    }
    __shared__ float4 red[4];
    int wid = threadIdx.x >> 6;
    if ((threadIdx.x & 63) == 0) red[wid] = make_float4(o, mg, tl, sh);
    __syncthreads();
    if (threadIdx.x == 0) {
        float4 r0 = red[0], r1 = red[1], r2 = red[2], r3 = red[3];
        partials[blockIdx.x] = make_float4(r0.x + r1.x + r2.x + r3.x,
                                           r0.y + r1.y + r2.y + r3.y,
                                           r0.z + r1.z + r2.z + r3.z,
                                           r0.w + r1.w + r2.w + r3.w);
    }
}

__global__ __launch_bounds__(256) void splloss_final(
    const float4* __restrict__ partials, int nb, float* __restrict__ out,
    double inv_bs, double inv_bd, double inv_shape)
{
    double o = 0.0, m = 0.0, t = 0.0, s = 0.0;
    for (int i = threadIdx.x; i < nb; i += 256) {
        float4 p = partials[i];
        o += (double)p.x; m += (double)p.y; t += (double)p.z; s += (double)p.w;
    }
    #pragma unroll
    for (int off = 32; off > 0; off >>= 1) {
        o += __shfl_down(o, off);
        m += __shfl_down(m, off);
        t += __shfl_down(t, off);
        s += __shfl_down(s, off);
    }
    __shared__ double red[4][4];
    int wid = threadIdx.x >> 6;
    if ((threadIdx.x & 63) == 0) { red[wid][0] = o; red[wid][1] = m; red[wid][2] = t; red[wid][3] = s; }
    __syncthreads();
    if (threadIdx.x == 0) {
        double ot = red[0][0] + red[1][0] + red[2][0] + red[3][0];
        double mt = red[0][1] + red[1][1] + red[2][1] + red[3][1];
        double tt = red[0][2] + red[1][2] + red[2][2] + red[3][2];
        double st = red[0][3] + red[1][3] + red[2][3] + red[3][3];
        double total = 1.0 * (ot * inv_bs)
                     + 2.0 * (mt * inv_bd)
                     + 1.0 * (tt * inv_bd)
                     + 0.5 * (st * inv_shape);
        out[0] = (float)total;
    }
}

extern "C" void kernel_launch(void* const* d_in, const int* in_sizes, int n_in,
                              void* d_out, int out_size, void* d_ws, size_t ws_size,
                              hipStream_t stream) {
    const float* yp = (const float*)d_in[0];
    const float* yt = (const float*)d_in[1];
    const float* dm = (const float*)d_in[2];
    float* out = (float*)d_out;

    int n = in_sizes[0];              // B*S; S divisible by 24
    int n_days = n / HOURS_;          // B*D
    int nb = (n_days + DPB - 1) / DPB;

    float4* partials = (float4*)d_ws; // nb * 16 bytes

    splloss_days<<<nb, 256, 0, stream>>>(yp, yt, dm, partials, n_days);

    double inv_bs    = 1.0 / (double)n;
    double inv_bd    = 1.0 / (double)n_days;
    double inv_shape = 1.0 / ((double)n_days + 1e-6);
    splloss_final<<<1, 256, 0, stream>>>(partials, nb, out, inv_bs, inv_bd, inv_shape);
}

// Round 5
// 268.324 us; speedup vs baseline: 1.0226x; 1.0226x over previous
//
#include <hip/hip_runtime.h>
#include <math.h>

// SoftPeakAwareLoss on MI355X — R3 resubmit (R3 bench hit GPU-acquisition
// timeout, never measured): 2-lanes-per-day, no LDS, no barriers.
// R0/R1 post-mortem: one-thread-per-day is latency-bound (600-inst serial
// chains, 18-deep load batches > VGPR budget -> serialized MLP; both pipes
// <25%). Here each day's 24 h is split across an even/odd lane pair:
// 3x float4 loads per array per lane (48B lane stride, L1 absorbs overlap),
// single shfl_xor(1) butterflies for cross-half reductions, analytic window
// count, grid-stride over days. Block reduce -> float4 partial -> 1-block
// finalize in double.

#define HOURS_ 24
#define WIN_ 2
#define NEGV (-1e9f)

__global__ __launch_bounds__(256) void splloss_days(
    const float* __restrict__ ypred,
    const float* __restrict__ ytrue,
    const float* __restrict__ isday,
    float4* __restrict__ partials,
    int n_days)
{
    const int tid  = threadIdx.x;
    const int half = tid & 1;                 // which 12-hour half this lane owns
    const int h0g  = half * 12;               // global hour offset of this half
    const int dayStride = (gridDim.x * 256) >> 1;

    float o = 0.f, mg = 0.f, tl = 0.f, sh = 0.f;

    for (int day = (blockIdx.x * 256 + tid) >> 1; day < n_days; day += dayStride) {
        // ---- load this lane's 12 hours of pred/true/mask (3x float4 each)
        const float4* p4 = reinterpret_cast<const float4*>(ypred + (size_t)day * 24 + h0g);
        const float4* t4 = reinterpret_cast<const float4*>(ytrue + (size_t)day * 24 + h0g);
        const float4* d4 = reinterpret_cast<const float4*>(isday + (size_t)day * 24 + h0g);
        float4 pa0 = p4[0], pa1 = p4[1], pa2 = p4[2];
        float4 ta0 = t4[0], ta1 = t4[1], ta2 = t4[2];
        float4 da0 = d4[0], da1 = d4[1], da2 = d4[2];

        float a[12] = {pa0.x, pa0.y, pa0.z, pa0.w, pa1.x, pa1.y, pa1.z, pa1.w,
                       pa2.x, pa2.y, pa2.z, pa2.w};
        float b[12] = {ta0.x, ta0.y, ta0.z, ta0.w, ta1.x, ta1.y, ta1.z, ta1.w,
                       ta2.x, ta2.y, ta2.z, ta2.w};
        float dm[12] = {da0.x, da0.y, da0.z, da0.w, da1.x, da1.y, da1.z, da1.w,
                        da2.x, da2.y, da2.z, da2.w};

        // ---- L_overall partial (per-lane own hours; no doubling)
        #pragma unroll
        for (int k = 0; k < 12; ++k) { float d = a[k] - b[k]; o += d * d; }

        // ---- masked local maxima + first-occurrence argmax of masked true
        float mt = -INFINITY, mp = -INFINITY;
        int pk = h0g;
        #pragma unroll
        for (int k = 0; k < 12; ++k) {
            bool dy = dm[k] > 0.5f;
            float bm = dy ? b[k] : NEGV;
            float am = dy ? a[k] : NEGV;
            if (bm > mt) { mt = bm; pk = h0g + k; }   // strict > = first occurrence
            mp = fmaxf(mp, am);
        }
        // butterfly with partner lane (both get combined result)
        {
            float mt_o = __shfl_xor(mt, 1);
            int   pk_o = __shfl_xor(pk, 1);
            float mp_o = __shfl_xor(mp, 1);
            bool takeo = (mt_o > mt) || (mt_o == mt && pk_o < pk);  // ties -> lower hour
            pk = takeo ? pk_o : pk;
            mt = fmaxf(mt, mt_o);
            mp = fmaxf(mp, mp_o);
        }

        // ---- soft peaks (softmax, TEMP=0.1 -> scale 10)
        float set = 0.f, syt = 0.f, sht = 0.f;
        float sep = 0.f, syp = 0.f, shp = 0.f;
        #pragma unroll
        for (int k = 0; k < 12; ++k) {
            bool dy = dm[k] > 0.5f;
            float bm = dy ? b[k] : NEGV;
            float am = dy ? a[k] : NEGV;
            float et = __expf((bm - mt) * 10.f);   // night -> exp(-1e10) = 0
            float ep = __expf((am - mp) * 10.f);
            float hh = (float)(h0g + k);
            set += et; syt += et * b[k]; sht += et * hh;
            sep += ep; syp += ep * a[k]; shp += ep * hh;
        }
        set += __shfl_xor(set, 1);
        syt += __shfl_xor(syt, 1);
        sht += __shfl_xor(sht, 1);
        sep += __shfl_xor(sep, 1);
        syp += __shfl_xor(syp, 1);
        shp += __shfl_xor(shp, 1);
        {
            float tv = syt / set, tt = sht / set;
            float pv = syp / sep, pt = shp / sep;
            float dmg = (pv - tv) * (pv - tv);
            float dtl = (pt - tt) * (pt - tt);
            // both lanes computed identical values -> count once
            mg += half ? 0.f : dmg;
            tl += half ? 0.f : dtl;
        }

        // ---- shape loss: window [pk-2, pk+2] clipped to [0,23]
        int lo = pk - WIN_; if (lo < 0) lo = 0;
        int hi = pk + WIN_; if (hi > 23) hi = 23;
        float cnt = (float)(hi - lo + 1);          // analytic window length
        float twmax = -INFINITY, pwmax = -INFINITY;
        #pragma unroll
        for (int k = 0; k < 12; ++k) {
            int hg = h0g + k;
            bool in = (hg >= lo) && (hg <= hi);
            twmax = in ? fmaxf(twmax, b[k]) : twmax;
            pwmax = in ? fmaxf(pwmax, a[k]) : pwmax;
        }
        twmax = fmaxf(twmax, __shfl_xor(twmax, 1));
        pwmax = fmaxf(pwmax, __shfl_xor(pwmax, 1));
        {
            float rt = 1.f / (twmax + 1e-6f);
            float rp = 1.f / (pwmax + 1e-6f);
            float ss = 0.f;
            #pragma unroll
            for (int k = 0; k < 12; ++k) {
                int hg = h0g + k;
                bool in = (hg >= lo) && (hg <= hi);
                float d = a[k] * rp - b[k] * rt;
                ss += in ? d * d : 0.f;
            }
            sh += ss / cnt;   // per-lane partial; (ssA+ssB)/cnt sums correctly
        }
    }

    // ---- block reduction: wave shuffle then LDS across the 4 waves
    #pragma unroll
    for (int off = 32; off > 0; off >>= 1) {
        o  += __shfl_down(o,  off);
        mg += __shfl_down(mg, off);
        tl += __shfl_down(tl, off);
        sh += __shfl_down(sh, off);
    }
    __shared__ float4 red[4];
    int wid = threadIdx.x >> 6;
    if ((threadIdx.x & 63) == 0) red[wid] = make_float4(o, mg, tl, sh);
    __syncthreads();
    if (threadIdx.x == 0) {
        float4 r0 = red[0], r1 = red[1], r2 = red[2], r3 = red[3];
        partials[blockIdx.x] = make_float4(r0.x + r1.x + r2.x + r3.x,
                                           r0.y + r1.y + r2.y + r3.y,
                                           r0.z + r1.z + r2.z + r3.z,
                                           r0.w + r1.w + r2.w + r3.w);
    }
}

__global__ __launch_bounds__(256) void splloss_final(
    const float4* __restrict__ partials, int nb, float* __restrict__ out,
    double inv_bs, double inv_bd, double inv_shape)
{
    double o = 0.0, m = 0.0, t = 0.0, s = 0.0;
    for (int i = threadIdx.x; i < nb; i += 256) {
        float4 p = partials[i];
        o += (double)p.x; m += (double)p.y; t += (double)p.z; s += (double)p.w;
    }
    #pragma unroll
    for (int off = 32; off > 0; off >>= 1) {
        o += __shfl_down(o, off);
        m += __shfl_down(m, off);
        t += __shfl_down(t, off);
        s += __shfl_down(s, off);
    }
    __shared__ double red[4][4];
    int wid = threadIdx.x >> 6;
    if ((threadIdx.x & 63) == 0) { red[wid][0] = o; red[wid][1] = m; red[wid][2] = t; red[wid][3] = s; }
    __syncthreads();
    if (threadIdx.x == 0) {
        double ot = red[0][0] + red[1][0] + red[2][0] + red[3][0];
        double mt = red[0][1] + red[1][1] + red[2][1] + red[3][1];
        double tt = red[0][2] + red[1][2] + red[2][2] + red[3][2];
        double st = red[0][3] + red[1][3] + red[2][3] + red[3][3];
        double total = 1.0 * (ot * inv_bs)
                     + 2.0 * (mt * inv_bd)
                     + 1.0 * (tt * inv_bd)
                     + 0.5 * (st * inv_shape);
        out[0] = (float)total;
    }
}

extern "C" void kernel_launch(void* const* d_in, const int* in_sizes, int n_in,
                              void* d_out, int out_size, void* d_ws, size_t ws_size,
                              hipStream_t stream) {
    const float* yp = (const float*)d_in[0];
    const float* yt = (const float*)d_in[1];
    const float* dm = (const float*)d_in[2];
    float* out = (float*)d_out;

    int n = in_sizes[0];              // B*S; S divisible by 24
    int n_days = n / HOURS_;          // B*D

    int nb = 1920;                    // 4 exact grid-stride passes at 983040 days
    int nbMax = (n_days + 127) / 128; // 128 days per block per pass
    if (nbMax < nb) nb = nbMax;

    float4* partials = (float4*)d_ws; // nb * 16 bytes

    splloss_days<<<nb, 256, 0, stream>>>(yp, yt, dm, partials, n_days);

    double inv_bs    = 1.0 / (double)n;
    double inv_bd    = 1.0 / (double)n_days;
    double inv_shape = 1.0 / ((double)n_days + 1e-6);
    splloss_final<<<1, 256, 0, stream>>>(partials, nb, out, inv_bs, inv_bd, inv_shape);
}